// Round 1
// baseline (237.614 us; speedup 1.0000x reference)
//
#include <hip/hip_runtime.h>
#include <hip/hip_bf16.h>
#include <math.h>

#define DT (1.0f / 60.0f)

typedef __bf16 bf16x8 __attribute__((ext_vector_type(8)));
typedef float f32x4 __attribute__((ext_vector_type(4)));

__device__ __forceinline__ void async_copy16(void* lds, const void* g) {
    __builtin_amdgcn_global_load_lds(
        (__attribute__((address_space(1))) void*)(g),
        (__attribute__((address_space(3))) void*)(lds),
        16, 0, 0);
}

// ---------------------------------------------------------------------------
// Weight prep: W (K x N fp32, row-major) -> Wt (N x Kpad bf16, k-contiguous)
// grid: 512 (W1t rows) + 512 (W2t rows) + 128 (W3t rows) blocks, 128 threads
// ---------------------------------------------------------------------------
__global__ void prep_weights(const float* __restrict__ W1,
                             const float* __restrict__ W2,
                             const float* __restrict__ W3,
                             __hip_bfloat16* __restrict__ W1t,
                             __hip_bfloat16* __restrict__ W2t,
                             __hip_bfloat16* __restrict__ W3t) {
    int b = blockIdx.x;
    int tid = threadIdx.x;
    if (b < 512) {
        int n = b;  // W1: 414x512 -> W1t: 512x416 (k 414..415 zero)
        for (int k = tid; k < 416; k += 128)
            W1t[n * 416 + k] = __float2bfloat16(k < 414 ? W1[k * 512 + n] : 0.0f);
    } else if (b < 1024) {
        int n = b - 512;  // W2: 512x512 -> W2t: 512x512
        for (int k = tid; k < 512; k += 128)
            W2t[n * 512 + k] = __float2bfloat16(W2[k * 512 + n]);
    } else {
        int n = b - 1024;  // W3: 512x120 -> W3t: 128x512 (rows 120..127 zero)
        for (int k = tid; k < 512; k += 128)
            W3t[n * 512 + k] = __float2bfloat16(n < 120 ? W3[k * 120 + n] : 0.0f);
    }
}

// ---------------------------------------------------------------------------
// Build x (B x 416 bf16): [0:300) = n_observation, [300:414) = quat 6d feats,
// [414:416) = zero pad. One block per batch row.
// ---------------------------------------------------------------------------
__global__ void build_x(const float* __restrict__ obs,
                        const float* __restrict__ action,
                        __hip_bfloat16* __restrict__ x) {
    int row = blockIdx.x;
    int tid = threadIdx.x;
    const float* o = obs + (size_t)row * 300;
    __hip_bfloat16* xr = x + (size_t)row * 416;
    for (int c = tid; c < 300; c += 128)
        xr[c] = __float2bfloat16(o[c]);
    if (tid < 19) {
        const float* a = action + (size_t)row * 57 + tid * 3;
        float rx = a[0], ry = a[1], rz = a[2];
        float ang = sqrtf(rx * rx + ry * ry + rz * rz);
        float half = 0.5f * ang;
        float s;
        if (ang < 1e-8f)
            s = 0.5f - ang * ang * (1.0f / 48.0f);
        else
            s = sinf(half) / ang;
        float qx = rx * s, qy = ry * s, qz = rz * s, qw = cosf(half);
        // flip_quat_by_w dropped: R(-q) == R(q), vec6d is quadratic in q.
        float r00 = 1.0f - 2.0f * (qy * qy + qz * qz);
        float r10 = 2.0f * (qx * qy + qz * qw);
        float r20 = 2.0f * (qx * qz - qy * qw);
        float r01 = 2.0f * (qx * qy - qz * qw);
        float r11 = 1.0f - 2.0f * (qx * qx + qz * qz);
        float r21 = 2.0f * (qy * qz + qx * qw);
        __hip_bfloat16* p = xr + 300 + tid * 6;
        p[0] = __float2bfloat16(r00);
        p[1] = __float2bfloat16(r01);
        p[2] = __float2bfloat16(r10);
        p[3] = __float2bfloat16(r11);
        p[4] = __float2bfloat16(r20);
        p[5] = __float2bfloat16(r21);
    } else if (tid == 19) {
        xr[414] = __float2bfloat16(0.0f);
        xr[415] = __float2bfloat16(0.0f);
    }
}

// ---------------------------------------------------------------------------
// GEMM: C(M x N) = A(M x K) * Bt(N x K)^T, bf16 in, fp32 acc.
// 128x128 tile per 256-thread block, 4 waves each computing 64x64 via
// 4x4 grid of 16x16x32 bf16 MFMAs. m97-style 2-barrier K-loop with
// global_load_lds width 16.
// EPI 0: C = relu(acc + bias) -> bf16, ldc cols
// EPI 1: C = (acc + bias) * scale + mean -> fp32, cols < N only
// ---------------------------------------------------------------------------
template <int KSTEPS, int EPI>
__global__ __launch_bounds__(256, 2) void gemm_k(
    const __hip_bfloat16* __restrict__ A, const __hip_bfloat16* __restrict__ Bt,
    const float* __restrict__ bias, __hip_bfloat16* __restrict__ Cb,
    float* __restrict__ Cf, const float* __restrict__ scale,
    const float* __restrict__ mean, int N, int ldc) {
    constexpr int K = KSTEPS * 32;
    __shared__ __hip_bfloat16 As[128 * 32];
    __shared__ __hip_bfloat16 Bs[128 * 32];
    const int tid = threadIdx.x;
    const int tileM = blockIdx.x * 128;
    const int tileN = blockIdx.y * 128;

    // staging: thread t fills LDS bytes [t*16, t*16+16) (+4096 for rows 64..127)
    const char* Agb = (const char*)(A + (size_t)tileM * K) +
                      (tid >> 2) * (K * 2) + (tid & 3) * 16;
    const char* Bgb = (const char*)(Bt + (size_t)tileN * K) +
                      (tid >> 2) * (K * 2) + (tid & 3) * 16;
    char* AsB = (char*)As + tid * 16;
    char* BsB = (char*)Bs + tid * 16;
    const int rstride = 64 * K * 2;

    const int lane = tid & 63;
    const int w = tid >> 6;
    const int wm = w >> 1, wn = w & 1;
    const int lrow = lane & 15, kgrp = lane >> 4;
    const __hip_bfloat16* Asf = As + (wm * 64 + lrow) * 32 + kgrp * 8;
    const __hip_bfloat16* Bsf = Bs + (wn * 64 + lrow) * 32 + kgrp * 8;

    f32x4 zero4 = {0.0f, 0.0f, 0.0f, 0.0f};
    f32x4 acc[4][4];
#pragma unroll
    for (int i = 0; i < 4; i++)
#pragma unroll
        for (int j = 0; j < 4; j++) acc[i][j] = zero4;

    for (int s = 0; s < KSTEPS; s++) {
        __syncthreads();  // previous iter's ds_reads done before overwrite
        async_copy16(AsB, Agb + s * 64);
        async_copy16(AsB + 4096, Agb + s * 64 + rstride);
        async_copy16(BsB, Bgb + s * 64);
        async_copy16(BsB + 4096, Bgb + s * 64 + rstride);
        __syncthreads();  // vmcnt(0) drained by barrier: LDS data ready
        bf16x8 af[4], bfv[4];
#pragma unroll
        for (int i = 0; i < 4; i++) {
            af[i] = *(const bf16x8*)(Asf + i * 16 * 32);
            bfv[i] = *(const bf16x8*)(Bsf + i * 16 * 32);
        }
#pragma unroll
        for (int i = 0; i < 4; i++)
#pragma unroll
            for (int j = 0; j < 4; j++)
                acc[i][j] = __builtin_amdgcn_mfma_f32_16x16x32_bf16(
                    af[i], bfv[j], acc[i][j], 0, 0, 0);
    }

    // epilogue. C/D layout: col = lane&15, row = (lane>>4)*4 + reg  [m89/m91]
#pragma unroll
    for (int j = 0; j < 4; j++) {
        int col = tileN + wn * 64 + j * 16 + lrow;
        if (EPI == 1 && col >= N) continue;
        float bb = bias[col];
        float sc = (EPI == 1) ? scale[col] : 0.0f;
        float mn = (EPI == 1) ? mean[col] : 0.0f;
#pragma unroll
        for (int i = 0; i < 4; i++) {
            int rbase = tileM + wm * 64 + i * 16 + kgrp * 4;
#pragma unroll
            for (int r = 0; r < 4; r++) {
                float v = acc[i][j][r] + bb;
                if (EPI == 0) {
                    v = v > 0.0f ? v : 0.0f;
                    Cb[(size_t)(rbase + r) * ldc + col] = __float2bfloat16(v);
                } else {
                    Cf[(size_t)(rbase + r) * ldc + col] = v * sc + mn;
                }
            }
        }
    }
}

// ---------------------------------------------------------------------------
// State integration: one thread per (row, body). Pure fp32 port of reference.
// ---------------------------------------------------------------------------
__device__ __forceinline__ void quat_apply3(float qx, float qy, float qz,
                                            float qw, float vx, float vy,
                                            float vz, float& ox, float& oy,
                                            float& oz) {
    float tx = 2.0f * (qy * vz - qz * vy);
    float ty = 2.0f * (qz * vx - qx * vz);
    float tz = 2.0f * (qx * vy - qy * vx);
    ox = vx + qw * tx + (qy * tz - qz * ty);
    oy = vy + qw * ty + (qz * tx - qx * tz);
    oz = vz + qw * tz + (qx * ty - qy * tx);
}

__global__ __launch_bounds__(256) void integrate_k(
    const float* __restrict__ state, const float* __restrict__ delta,
    float* __restrict__ out, int total) {
    int idx = blockIdx.x * 256 + threadIdx.x;
    if (idx >= total) return;
    int row = idx / 20;
    int body = idx - row * 20;
    const float* sb = state + (size_t)row * 260 + body * 13;
    const float* rq = state + (size_t)row * 260 + 3;  // root quat (body 0)
    float qx = rq[0], qy = rq[1], qz = rq[2], qw = rq[3];
    const float* d = delta + (size_t)row * 120 + body * 6;

    float lx, ly, lz, ax, ay, az;
    quat_apply3(qx, qy, qz, qw, d[0], d[1], d[2], lx, ly, lz);
    quat_apply3(qx, qy, qz, qw, d[3], d[4], d[5], ax, ay, az);

    float vx = sb[7] + lx, vy = sb[8] + ly, vz = sb[9] + lz;
    float wx = sb[10] + ax, wy = sb[11] + ay, wz = sb[12] + az;
    float px = sb[0] + vx * DT, py = sb[1] + vy * DT, pz = sb[2] + vz * DT;

    float rx = sb[3], ry = sb[4], rz = sb[5], rw = sb[6];
    // dq = quat_multiply((w,0), rot):  v = rot.w*w + cross(w, rot.xyz),
    //                                  s = -dot(w, rot.xyz)
    float dqx = rw * wx + (wy * rz - wz * ry);
    float dqy = rw * wy + (wz * rx - wx * rz);
    float dqz = rw * wz + (wx * ry - wy * rx);
    float dqw = -(wx * rx + wy * ry + wz * rz);
    float h = 0.5f * DT;
    float nx = rx + h * dqx, ny = ry + h * dqy, nz = rz + h * dqz,
          nw = rw + h * dqw;
    float inv = 1.0f / sqrtf(nx * nx + ny * ny + nz * nz + nw * nw);

    float* o = out + (size_t)row * 260 + body * 13;
    o[0] = px;
    o[1] = py;
    o[2] = pz;
    o[3] = nx * inv;
    o[4] = ny * inv;
    o[5] = nz * inv;
    o[6] = nw * inv;
    o[7] = vx;
    o[8] = vy;
    o[9] = vz;
    o[10] = wx;
    o[11] = wy;
    o[12] = wz;
}

// ---------------------------------------------------------------------------
extern "C" void kernel_launch(void* const* d_in, const int* in_sizes, int n_in,
                              void* d_out, int out_size, void* d_ws,
                              size_t ws_size, hipStream_t stream) {
    const float* state = (const float*)d_in[0];
    const float* action = (const float*)d_in[1];
    const float* obs = (const float*)d_in[2];
    const float* W1 = (const float*)d_in[3];
    const float* b1 = (const float*)d_in[4];
    const float* W2 = (const float*)d_in[5];
    const float* b2 = (const float*)d_in[6];
    const float* W3 = (const float*)d_in[7];
    const float* b3 = (const float*)d_in[8];
    const float* dmean = (const float*)d_in[9];
    const float* dstd = (const float*)d_in[10];
    float* out = (float*)d_out;
    char* ws = (char*)d_ws;

    const int B = in_sizes[1] / 57;  // 32768

    // workspace layout (16B-aligned offsets)
    __hip_bfloat16* W1t = (__hip_bfloat16*)(ws);                  // 512x416
    __hip_bfloat16* W2t = (__hip_bfloat16*)(ws + 425984);         // 512x512
    __hip_bfloat16* W3t = (__hip_bfloat16*)(ws + 950272);         // 128x512
    __hip_bfloat16* x = (__hip_bfloat16*)(ws + 1081344);          // B x 416
    __hip_bfloat16* h1 = (__hip_bfloat16*)(ws + 1081344 + 33554432);  // B x 512
    float* delta = (float*)(ws + 1081344 + 2 * 33554432);         // B x 120
    __hip_bfloat16* h2 = x;  // h2 aliases x (x dead after GEMM1)

    prep_weights<<<1152, 128, 0, stream>>>(W1, W2, W3, W1t, W2t, W3t);
    build_x<<<B, 128, 0, stream>>>(obs, action, x);

    dim3 g1(B / 128, 4);
    gemm_k<13, 0><<<g1, 256, 0, stream>>>(x, W1t, b1, h1, nullptr, nullptr,
                                          nullptr, 512, 512);
    dim3 g2(B / 128, 4);
    gemm_k<16, 0><<<g2, 256, 0, stream>>>(h1, W2t, b2, h2, nullptr, nullptr,
                                          nullptr, 512, 512);
    dim3 g3(B / 128, 1);
    gemm_k<16, 1><<<g3, 256, 0, stream>>>(h2, W3t, b3, nullptr, delta, dstd,
                                          dmean, 120, 120);

    int total = B * 20;
    integrate_k<<<(total + 255) / 256, 256, 0, stream>>>(state, delta, out,
                                                         total);
}